// Round 7
// baseline (353.695 us; speedup 1.0000x reference)
//
#include <hip/hip_runtime.h>
#include <math.h>

#define BB 16
#define SS 512
#define HH 768
#define WW 256
#define VV 32000
#define NROWS (BB*WW)          // 4096
#define NCHUNK 500             // 64-wide v chunks
#define BM 256
#define BN 128
#define BK 32
#define NKT (HH/BK)            // 24
#define NMT (NROWS/BM)         // 16
#define NVT (VV/BN)            // 250
#define NWG (NMT*NVT)          // 4000

typedef __attribute__((ext_vector_type(8))) short short8;
typedef __attribute__((ext_vector_type(4))) float f32x4;

__device__ __forceinline__ unsigned short f2bf(float x) {
    union { float f; unsigned int u; } c; c.f = x;
    unsigned int r = c.u + 0x7FFFu + ((c.u >> 16) & 1u);
    return (unsigned short)(r >> 16);
}

#define GLOAD16(g, l) __builtin_amdgcn_global_load_lds( \
    (const __attribute__((address_space(1))) void*)(g), \
    (__attribute__((address_space(3))) void*)(l), 16, 0, 0)

// ---------------- pooling: one block per (b, w), binary search over sorted wid ----------------
__global__ __launch_bounds__(256) void pool_kernel(
    const float* __restrict__ h, const int* __restrict__ wid,
    unsigned short* __restrict__ pooled)
{
    int blk = blockIdx.x;
    int b = blk >> 8;
    int w = blk & 255;
    int tid = threadIdx.x;
    __shared__ int s_wid[SS];
    for (int i = tid; i < SS; i += 256) s_wid[i] = wid[b*SS + i];
    __syncthreads();
    int lo = 0, hi = SS;
    while (lo < hi) { int mid = (lo + hi) >> 1; if (s_wid[mid] < w) lo = mid + 1; else hi = mid; }
    int start = lo;
    hi = SS;
    while (lo < hi) { int mid = (lo + hi) >> 1; if (s_wid[mid] <= w) lo = mid + 1; else hi = mid; }
    int end = lo;
    int cnt = end - start;

    if (tid < 192) {
        float4 a = {0.f, 0.f, 0.f, 0.f};
        const float* hb = h + (size_t)b*SS*HH;
        for (int s = start; s < end; ++s) {
            float4 r = *(const float4*)&hb[(size_t)s*HH + tid*4];
            a.x += r.x; a.y += r.y; a.z += r.z; a.w += r.w;
        }
        float inv = (cnt > 0) ? (1.0f / (float)cnt) : 0.0f;
        ushort4 o;
        o.x = f2bf(a.x*inv); o.y = f2bf(a.y*inv);
        o.z = f2bf(a.z*inv); o.w = f2bf(a.w*inv);
        *(ushort4*)&pooled[(size_t)blk*HH + tid*4] = o;
    }
}

// ---------------- convert + transpose W: (768,32000) f32 -> (32000,768) bf16 ----------------
__global__ __launch_bounds__(256) void wt_kernel(
    const float* __restrict__ Wc, unsigned short* __restrict__ Wt)
{
    const int v0 = blockIdx.x * 64;
    const int k0 = blockIdx.y * 64;
    const int t = threadIdx.x;
    __shared__ unsigned short S[64][72];
    #pragma unroll
    for (int j = 0; j < 4; ++j) {
        int idx = t + j*256;
        int kr = idx >> 4;
        int vs = idx & 15;
        float4 f = *(const float4*)&Wc[(size_t)(k0+kr)*VV + v0 + vs*4];
        S[kr][vs*4+0] = f2bf(f.x);
        S[kr][vs*4+1] = f2bf(f.y);
        S[kr][vs*4+2] = f2bf(f.z);
        S[kr][vs*4+3] = f2bf(f.w);
    }
    __syncthreads();
    #pragma unroll
    for (int j = 0; j < 2; ++j) {
        int idx = t + j*256;
        int vi = idx >> 3;
        int ks = idx & 7;
        short8 o;
        #pragma unroll
        for (int i = 0; i < 8; ++i) o[i] = (short)S[ks*8+i][vi];
        *(short8*)&Wt[(size_t)(v0+vi)*HH + k0 + ks*8] = o;
    }
}

// ---------------- MFMA GEMM, 256x128 tile, m97-style loop, 3 blocks/CU ----------------
// 256 threads = 4 waves (2M x 2N), wave tile 128x64, BK=32.
// LDS: 2 dbuf x (A 16KB + B 8KB) = 48 KB -> 3 blocks/CU; launch_bounds(256,3)
// caps VGPR ~170 -> 12 waves/CU: three independent barrier groups hide each
// other's stage/drain latency (m97 mechanism). No manual waitcnt/setprio.
// Swizzle: LDS slot (row, seg) holds global seg (seg ^ ((row>>1)&3)); gives
// 2-way (free) bank aliasing on ds_read_b128 at BK=32.
__global__ __launch_bounds__(256, 3) void logits_kernel(
    const unsigned short* __restrict__ Pb, const unsigned short* __restrict__ Wt,
    const float* __restrict__ bc, const int* __restrict__ targets,
    float* __restrict__ pmax, float* __restrict__ psum,
    float* __restrict__ tlogit)
{
    __shared__ unsigned short Alds[2][BM*BK];   // 2 x 16 KB
    __shared__ unsigned short Blds[2][BN*BK];   // 2 x 8 KB

    // XCD swizzle (NWG = 4000, divisible by 8), m-minor within XCD chunk
    const int id = blockIdx.x;
    const int wg = (id & 7) * (NWG/8) + (id >> 3);
    const int mt = wg % NMT;
    const int vt = wg / NMT;

    const int t = threadIdx.x;
    const int w = t >> 6;           // wave 0..3
    const int lane = t & 63;
    const int r16 = lane & 15;
    const int kb = lane >> 4;       // 0..3 (8-bf16 seg index)
    const int wr = w >> 1;          // 0..1 (M)
    const int wc = w & 1;           // 0..1 (N)
    const int row0 = mt * BM;
    const int v0 = vt * BN;

    // staging: each wave-call covers 16 rows x 32 k (1 KB); lane = r*4+s
    const int rr = lane >> 2;                 // 0..15 row within call
    const int sg = (lane & 3) ^ ((rr >> 1) & 3);  // pre-swizzled global seg

    // A: 16 calls (4/wave), B: 8 calls (2/wave)
    #define STAGE(BUF, KT) do {                                                   \
        const int k0_ = (KT) * BK;                                                \
        _Pragma("unroll")                                                         \
        for (int j_ = 0; j_ < 4; ++j_) {                                          \
            int ca_ = w*4 + j_;                                                   \
            GLOAD16(Pb + (size_t)(row0 + ca_*16 + rr)*HH + k0_ + sg*8,            \
                    &Alds[BUF][ca_*512]);                                         \
        }                                                                         \
        _Pragma("unroll")                                                         \
        for (int j_ = 0; j_ < 2; ++j_) {                                          \
            int cb_ = w*2 + j_;                                                   \
            GLOAD16(Wt + (size_t)(v0 + cb_*16 + rr)*HH + k0_ + sg*8,              \
                    &Blds[BUF][cb_*512]);                                         \
        }                                                                         \
    } while (0)

    f32x4 acc[8][4];
    #pragma unroll
    for (int mf = 0; mf < 8; ++mf)
        #pragma unroll
        for (int nf = 0; nf < 4; ++nf)
            acc[mf][nf] = (f32x4){0.f, 0.f, 0.f, 0.f};

    STAGE(0, 0);
    __syncthreads();

    const int rseg = (kb ^ ((r16 >> 1) & 3)) * 8;   // swizzled k-seg on read side

    for (int kt = 0; kt < NKT; ++kt) {
        const int buf = kt & 1;
        if (kt + 1 < NKT) STAGE(buf ^ 1, kt + 1);

        short8 af[8], bfv[4];
        #pragma unroll
        for (int mf = 0; mf < 8; ++mf)
            af[mf] = *(const short8*)&Alds[buf][(wr*128 + mf*16 + r16)*BK + rseg];
        #pragma unroll
        for (int nf = 0; nf < 4; ++nf)
            bfv[nf] = *(const short8*)&Blds[buf][(wc*64 + nf*16 + r16)*BK + rseg];

        #pragma unroll
        for (int mf = 0; mf < 8; ++mf)
            #pragma unroll
            for (int nf = 0; nf < 4; ++nf)
                acc[mf][nf] = __builtin_amdgcn_mfma_f32_16x16x32_bf16(
                    af[mf], bfv[nf], acc[mf][nf], 0, 0, 0);

        __syncthreads();
    }

    // epilogue: bias + per-row max/sumexp over this wave's 64 cols (one chunk)
    const int cchunk = vt*2 + wc;
    float bias[4];
    #pragma unroll
    for (int nf = 0; nf < 4; ++nf) bias[nf] = bc[v0 + wc*64 + nf*16 + r16];

    #pragma unroll
    for (int mf = 0; mf < 8; ++mf) {
        #pragma unroll
        for (int j = 0; j < 4; ++j) {
            const int row = row0 + wr*128 + mf*16 + kb*4 + j;
            float v[4]; float mx = -INFINITY;
            #pragma unroll
            for (int nf = 0; nf < 4; ++nf) {
                v[nf] = acc[mf][nf][j] + bias[nf];
                mx = fmaxf(mx, v[nf]);
            }
            #pragma unroll
            for (int off = 1; off < 16; off <<= 1)
                mx = fmaxf(mx, __shfl_xor(mx, off, 16));
            float se = 0.f;
            #pragma unroll
            for (int nf = 0; nf < 4; ++nf) se += __expf(v[nf] - mx);
            #pragma unroll
            for (int off = 1; off < 16; off <<= 1)
                se += __shfl_xor(se, off, 16);
            if (r16 == 0) {
                pmax[(size_t)row*NCHUNK + cchunk] = mx;
                psum[(size_t)row*NCHUNK + cchunk] = se;
            }
            int tg = targets[row];
            int base = v0 + wc*64 + r16;
            #pragma unroll
            for (int nf = 0; nf < 4; ++nf)
                if (tg == base + nf*16) tlogit[row] = v[nf];
        }
    }
}

// ---------------- combine chunk partials -> per-row loss ----------------
__global__ __launch_bounds__(256) void reduce_kernel(
    const float* __restrict__ pmax, const float* __restrict__ psum,
    const float* __restrict__ tlogit, const int* __restrict__ targets,
    float* __restrict__ rowloss)
{
    const int row = blockIdx.x;
    const int tid = threadIdx.x;
    float m0 = (tid       < NCHUNK) ? pmax[(size_t)row*NCHUNK + tid]       : -INFINITY;
    float m1 = (tid + 256 < NCHUNK) ? pmax[(size_t)row*NCHUNK + tid + 256] : -INFINITY;
    float mw = fmaxf(m0, m1);
    #pragma unroll
    for (int off = 1; off < 64; off <<= 1)
        mw = fmaxf(mw, __shfl_xor(mw, off));
    __shared__ float smax[4];
    __shared__ float ssum[4];
    const int wave = tid >> 6;
    if ((tid & 63) == 0) smax[wave] = mw;
    __syncthreads();
    float mx = fmaxf(fmaxf(smax[0], smax[1]), fmaxf(smax[2], smax[3]));
    float s = 0.f;
    if (tid       < NCHUNK) s += psum[(size_t)row*NCHUNK + tid]       * __expf(m0 - mx);
    if (tid + 256 < NCHUNK) s += psum[(size_t)row*NCHUNK + tid + 256] * __expf(m1 - mx);
    #pragma unroll
    for (int off = 1; off < 64; off <<= 1)
        s += __shfl_xor(s, off);
    if ((tid & 63) == 0) ssum[wave] = s;
    __syncthreads();
    if (tid == 0) {
        float st = ssum[0] + ssum[1] + ssum[2] + ssum[3];
        float lse = mx + logf(st);
        int tg = targets[row];
        rowloss[row] = (tg != 0) ? (lse - tlogit[row]) : 0.0f;
    }
}

// ---------------- final sum over rows ----------------
__global__ __launch_bounds__(256) void finalize_kernel(
    const float* __restrict__ rowloss, const int* __restrict__ targets,
    float* __restrict__ out)
{
    const int tid = threadIdx.x;
    float s = 0.f; float c = 0.f;
    for (int i = tid; i < NROWS; i += 256) {
        s += rowloss[i];
        c += (targets[i] != 0) ? 1.0f : 0.0f;
    }
    #pragma unroll
    for (int off = 1; off < 64; off <<= 1) {
        s += __shfl_xor(s, off);
        c += __shfl_xor(c, off);
    }
    __shared__ float ss[4], sc[4];
    const int wave = tid >> 6;
    if ((tid & 63) == 0) { ss[wave] = s; sc[wave] = c; }
    __syncthreads();
    if (tid == 0) {
        float st = ss[0]+ss[1]+ss[2]+ss[3];
        float ct = sc[0]+sc[1]+sc[2]+sc[3];
        out[0] = st / fmaxf(ct, 1.0f);
    }
}

extern "C" void kernel_launch(void* const* d_in, const int* in_sizes, int n_in,
                              void* d_out, int out_size, void* d_ws, size_t ws_size,
                              hipStream_t stream) {
    const float* h       = (const float*)d_in[0];   // (16,512,768) f32
    const int*   wid     = (const int*)  d_in[1];   // (16,512) i32
    const int*   targets = (const int*)  d_in[2];   // (16,256) i32
    const float* Wc      = (const float*)d_in[3];   // (768,32000) f32
    const float* bc      = (const float*)d_in[4];   // (32000,) f32
    float* out = (float*)d_out;

    unsigned short* pooled = (unsigned short*)d_ws;              // 4096*768 bf16
    unsigned short* Wt     = pooled + (size_t)NROWS*HH;          // 32000*768 bf16
    float* pmax  = (float*)(Wt + (size_t)HH*VV);                 // 4096*500
    float* psum  = pmax + (size_t)NROWS*NCHUNK;                  // 4096*500
    float* tlog  = psum + (size_t)NROWS*NCHUNK;                  // 4096
    float* rowl  = tlog + NROWS;                                 // 4096

    pool_kernel<<<NROWS, 256, 0, stream>>>(h, wid, pooled);
    wt_kernel<<<dim3(VV/64, HH/64), 256, 0, stream>>>(Wc, Wt);
    logits_kernel<<<NWG, 256, 0, stream>>>(
        pooled, Wt, bc, targets, pmax, psum, tlog);
    reduce_kernel<<<NROWS, 256, 0, stream>>>(pmax, psum, tlog, targets, rowl);
    finalize_kernel<<<1, 256, 0, stream>>>(rowl, targets, out);
}

// Round 8
// 243.569 us; speedup vs baseline: 1.4521x; 1.4521x over previous
//
#include <hip/hip_runtime.h>
#include <math.h>

#define BB 16
#define SS 512
#define HH 768
#define WW 256
#define VV 32000
#define NROWS (BB*WW)          // 4096
#define NCHUNK 500             // 64-wide v chunks
#define BM 256
#define BN 128
#define BK 64                  // fp8: 64 bytes per row per k-tile
#define NKT (HH/BK)            // 12
#define NMT (NROWS/BM)         // 16
#define NVT (VV/BN)            // 250
#define NWG (NMT*NVT)          // 4000
#define WSCALE 64.0f
#define WISCALE (1.0f/64.0f)

typedef __attribute__((ext_vector_type(4))) float f32x4;

#define GLOAD16(g, l) __builtin_amdgcn_global_load_lds( \
    (const __attribute__((address_space(1))) void*)(g), \
    (__attribute__((address_space(3))) void*)(l), 16, 0, 0)

// pack 4 floats -> 4 fp8 e4m3 bytes (OCP)
__device__ __forceinline__ unsigned int pk4_fp8(float a0, float a1, float a2, float a3) {
    int r = __builtin_amdgcn_cvt_pk_fp8_f32(a0, a1, 0, false);
    r = __builtin_amdgcn_cvt_pk_fp8_f32(a2, a3, r, true);
    return (unsigned int)r;
}

// ---------------- pooling: one block per (b, w), fp8 output ----------------
__global__ __launch_bounds__(256) void pool_kernel(
    const float* __restrict__ h, const int* __restrict__ wid,
    unsigned int* __restrict__ pooled32)   // 4096 x 192 u32 (=768 fp8)
{
    int blk = blockIdx.x;
    int b = blk >> 8;
    int w = blk & 255;
    int tid = threadIdx.x;
    __shared__ int s_wid[SS];
    for (int i = tid; i < SS; i += 256) s_wid[i] = wid[b*SS + i];
    __syncthreads();
    int lo = 0, hi = SS;
    while (lo < hi) { int mid = (lo + hi) >> 1; if (s_wid[mid] < w) lo = mid + 1; else hi = mid; }
    int start = lo;
    hi = SS;
    while (lo < hi) { int mid = (lo + hi) >> 1; if (s_wid[mid] <= w) lo = mid + 1; else hi = mid; }
    int end = lo;
    int cnt = end - start;

    if (tid < 192) {
        float4 a = {0.f, 0.f, 0.f, 0.f};
        const float* hb = h + (size_t)b*SS*HH;
        for (int s = start; s < end; ++s) {
            float4 r = *(const float4*)&hb[(size_t)s*HH + tid*4];
            a.x += r.x; a.y += r.y; a.z += r.z; a.w += r.w;
        }
        float inv = (cnt > 0) ? (1.0f / (float)cnt) : 0.0f;
        pooled32[blk*192 + tid] = pk4_fp8(a.x*inv, a.y*inv, a.z*inv, a.w*inv);
    }
}

// ------- convert + transpose W: (768,32000) f32 -> (32000,768) fp8 (x64 scale) -------
__global__ __launch_bounds__(256) void wt_kernel(
    const float* __restrict__ Wc, unsigned char* __restrict__ Wt)
{
    const int v0 = blockIdx.x * 64;
    const int k0 = blockIdx.y * 64;
    const int t = threadIdx.x;
    __shared__ float S[64][65];
    #pragma unroll
    for (int j = 0; j < 4; ++j) {
        int idx = t + j*256;
        int kr = idx >> 4;
        int vs = idx & 15;
        float4 f = *(const float4*)&Wc[(size_t)(k0+kr)*VV + v0 + vs*4];
        S[kr][vs*4+0] = f.x; S[kr][vs*4+1] = f.y;
        S[kr][vs*4+2] = f.z; S[kr][vs*4+3] = f.w;
    }
    __syncthreads();
    #pragma unroll
    for (int j = 0; j < 2; ++j) {
        int idx = t + j*256;
        int vi = idx >> 3;     // 0..63
        int ks = idx & 7;      // 0..7
        float f[8];
        #pragma unroll
        for (int i = 0; i < 8; ++i) f[i] = S[ks*8+i][vi] * WSCALE;
        uint2 o;
        o.x = pk4_fp8(f[0], f[1], f[2], f[3]);
        o.y = pk4_fp8(f[4], f[5], f[6], f[7]);
        *(uint2*)&Wt[(size_t)(v0+vi)*HH + k0 + ks*8] = o;
    }
}

// ---------------- fp8 MFMA GEMM, 256x128 tile, BK=64, 2 blocks/CU ----------------
// 512 threads = 8 waves (4M x 2N), wave tile 64x64, acc[4][4]=64 VGPR.
// LDS: 2 dbuf x (A 16KB + B 8KB) = 48 KB -> 2 blocks/CU; launch_bounds(512,4)
// caps VGPR at 128 -> 16 waves/CU. m97-style loop: depth-1 prefetch, compiler
// waits, one barrier per k-step; inter-block desync hides drains.
// Swizzle: 16B seg s at row r holds global seg s^((r>>1)&3); read side XORs same.
__global__ __launch_bounds__(512, 4) void logits_kernel(
    const unsigned char* __restrict__ Pb, const unsigned char* __restrict__ Wt,
    const float* __restrict__ bc, const int* __restrict__ targets,
    float* __restrict__ pmax, float* __restrict__ psum,
    float* __restrict__ tlogit)
{
    __shared__ unsigned char Alds[2][BM*BK];   // 2 x 16 KB
    __shared__ unsigned char Blds[2][BN*BK];   // 2 x 8 KB

    // XCD swizzle (NWG = 4000, divisible by 8), m-minor within XCD chunk
    const int id = blockIdx.x;
    const int wg = (id & 7) * (NWG/8) + (id >> 3);
    const int mt = wg % NMT;
    const int vt = wg / NMT;

    const int t = threadIdx.x;
    const int w = t >> 6;           // wave 0..7
    const int lane = t & 63;
    const int r16 = lane & 15;
    const int kb = lane >> 4;       // 0..3 (8-byte k-seg within 32)
    const int wr = w >> 1;          // 0..3 (M)
    const int wc = w & 1;           // 0..1 (N)
    const int row0 = mt * BM;
    const int v0 = vt * BN;

    // staging: one call = 64 lanes x 16 B = 16 rows x 64 B; lane = rr*4 + s
    const int rr = lane >> 2;                     // 0..15 row within call
    const int sg = (lane & 3) ^ ((rr >> 1) & 3);  // pre-swizzled global 16B seg

    // A: 16 calls (2/wave), B: 8 calls (1/wave)
    #define STAGE(BUF, KT) do {                                                   \
        const int k0_ = (KT) * BK;                                                \
        _Pragma("unroll")                                                         \
        for (int j_ = 0; j_ < 2; ++j_) {                                          \
            int ca_ = w*2 + j_;                                                   \
            GLOAD16(Pb + (size_t)(row0 + ca_*16 + rr)*HH + k0_ + sg*16,           \
                    &Alds[BUF][ca_*1024]);                                        \
        }                                                                         \
        GLOAD16(Wt + (size_t)(v0 + w*16 + rr)*HH + k0_ + sg*16,                   \
                &Blds[BUF][w*1024]);                                              \
    } while (0)

    f32x4 acc[4][4];
    #pragma unroll
    for (int mf = 0; mf < 4; ++mf)
        #pragma unroll
        for (int nf = 0; nf < 4; ++nf)
            acc[mf][nf] = (f32x4){0.f, 0.f, 0.f, 0.f};

    STAGE(0, 0);
    __syncthreads();

    const int swz = ((r16 >> 1) & 3);

    for (int kt = 0; kt < NKT; ++kt) {
        const int buf = kt & 1;
        if (kt + 1 < NKT) STAGE(buf ^ 1, kt + 1);

        long af[4][2], bfv[4][2];
        #pragma unroll
        for (int ks = 0; ks < 2; ++ks) {
            const int idx8 = ks*4 + kb;                       // 0..7
            const int off = ((idx8 >> 1) ^ swz)*16 + (idx8 & 1)*8;
            #pragma unroll
            for (int mf = 0; mf < 4; ++mf)
                af[mf][ks] = *(const long*)&Alds[buf][(wr*64 + mf*16 + r16)*BK + off];
            #pragma unroll
            for (int nf = 0; nf < 4; ++nf)
                bfv[nf][ks] = *(const long*)&Blds[buf][(wc*64 + nf*16 + r16)*BK + off];
        }

        #pragma unroll
        for (int ks = 0; ks < 2; ++ks)
            #pragma unroll
            for (int mf = 0; mf < 4; ++mf)
                #pragma unroll
                for (int nf = 0; nf < 4; ++nf)
                    acc[mf][nf] = __builtin_amdgcn_mfma_f32_16x16x32_fp8_fp8(
                        af[mf][ks], bfv[nf][ks], acc[mf][nf], 0, 0, 0);

        __syncthreads();
    }

    // epilogue: unscale + bias + per-row max/sumexp over this wave's 64 cols
    const int cchunk = vt*2 + wc;
    float bias[4];
    #pragma unroll
    for (int nf = 0; nf < 4; ++nf) bias[nf] = bc[v0 + wc*64 + nf*16 + r16];

    #pragma unroll
    for (int mf = 0; mf < 4; ++mf) {
        #pragma unroll
        for (int j = 0; j < 4; ++j) {
            const int row = row0 + wr*64 + mf*16 + kb*4 + j;
            float v[4]; float mx = -INFINITY;
            #pragma unroll
            for (int nf = 0; nf < 4; ++nf) {
                v[nf] = acc[mf][nf][j]*WISCALE + bias[nf];
                mx = fmaxf(mx, v[nf]);
            }
            #pragma unroll
            for (int off = 1; off < 16; off <<= 1)
                mx = fmaxf(mx, __shfl_xor(mx, off, 16));
            float se = 0.f;
            #pragma unroll
            for (int nf = 0; nf < 4; ++nf) se += __expf(v[nf] - mx);
            #pragma unroll
            for (int off = 1; off < 16; off <<= 1)
                se += __shfl_xor(se, off, 16);
            if (r16 == 0) {
                pmax[(size_t)row*NCHUNK + cchunk] = mx;
                psum[(size_t)row*NCHUNK + cchunk] = se;
            }
            int tg = targets[row];
            int base = v0 + wc*64 + r16;
            #pragma unroll
            for (int nf = 0; nf < 4; ++nf)
                if (tg == base + nf*16) tlogit[row] = v[nf];
        }
    }
}

// ---------------- combine chunk partials -> per-row loss ----------------
__global__ __launch_bounds__(256) void reduce_kernel(
    const float* __restrict__ pmax, const float* __restrict__ psum,
    const float* __restrict__ tlogit, const int* __restrict__ targets,
    float* __restrict__ rowloss)
{
    const int row = blockIdx.x;
    const int tid = threadIdx.x;
    float m0 = (tid       < NCHUNK) ? pmax[(size_t)row*NCHUNK + tid]       : -INFINITY;
    float m1 = (tid + 256 < NCHUNK) ? pmax[(size_t)row*NCHUNK + tid + 256] : -INFINITY;
    float mw = fmaxf(m0, m1);
    #pragma unroll
    for (int off = 1; off < 64; off <<= 1)
        mw = fmaxf(mw, __shfl_xor(mw, off));
    __shared__ float smax[4];
    __shared__ float ssum[4];
    const int wave = tid >> 6;
    if ((tid & 63) == 0) smax[wave] = mw;
    __syncthreads();
    float mx = fmaxf(fmaxf(smax[0], smax[1]), fmaxf(smax[2], smax[3]));
    float s = 0.f;
    if (tid       < NCHUNK) s += psum[(size_t)row*NCHUNK + tid]       * __expf(m0 - mx);
    if (tid + 256 < NCHUNK) s += psum[(size_t)row*NCHUNK + tid + 256] * __expf(m1 - mx);
    #pragma unroll
    for (int off = 1; off < 64; off <<= 1)
        s += __shfl_xor(s, off);
    if ((tid & 63) == 0) ssum[wave] = s;
    __syncthreads();
    if (tid == 0) {
        float st = ssum[0] + ssum[1] + ssum[2] + ssum[3];
        float lse = mx + logf(st);
        int tg = targets[row];
        rowloss[row] = (tg != 0) ? (lse - tlogit[row]) : 0.0f;
    }
}

// ---------------- final sum over rows ----------------
__global__ __launch_bounds__(256) void finalize_kernel(
    const float* __restrict__ rowloss, const int* __restrict__ targets,
    float* __restrict__ out)
{
    const int tid = threadIdx.x;
    float s = 0.f; float c = 0.f;
    for (int i = tid; i < NROWS; i += 256) {
        s += rowloss[i];
        c += (targets[i] != 0) ? 1.0f : 0.0f;
    }
    #pragma unroll
    for (int off = 1; off < 64; off <<= 1) {
        s += __shfl_xor(s, off);
        c += __shfl_xor(c, off);
    }
    __shared__ float ss[4], sc[4];
    const int wave = tid >> 6;
    if ((tid & 63) == 0) { ss[wave] = s; sc[wave] = c; }
    __syncthreads();
    if (tid == 0) {
        float st = ss[0]+ss[1]+ss[2]+ss[3];
        float ct = sc[0]+sc[1]+sc[2]+sc[3];
        out[0] = st / fmaxf(ct, 1.0f);
    }
}

extern "C" void kernel_launch(void* const* d_in, const int* in_sizes, int n_in,
                              void* d_out, int out_size, void* d_ws, size_t ws_size,
                              hipStream_t stream) {
    const float* h       = (const float*)d_in[0];   // (16,512,768) f32
    const int*   wid     = (const int*)  d_in[1];   // (16,512) i32
    const int*   targets = (const int*)  d_in[2];   // (16,256) i32
    const float* Wc      = (const float*)d_in[3];   // (768,32000) f32
    const float* bc      = (const float*)d_in[4];   // (32000,) f32
    float* out = (float*)d_out;

    unsigned char* pooled = (unsigned char*)d_ws;                // 4096*768 fp8
    unsigned char* Wt     = pooled + (size_t)NROWS*HH;           // 32000*768 fp8
    float* pmax  = (float*)(Wt + (size_t)HH*VV);                 // 4096*500
    float* psum  = pmax + (size_t)NROWS*NCHUNK;                  // 4096*500
    float* tlog  = psum + (size_t)NROWS*NCHUNK;                  // 4096
    float* rowl  = tlog + NROWS;                                 // 4096

    pool_kernel<<<NROWS, 256, 0, stream>>>(h, wid, (unsigned int*)pooled);
    wt_kernel<<<dim3(VV/64, HH/64), 256, 0, stream>>>(Wc, Wt);
    logits_kernel<<<NWG, 512, 0, stream>>>(
        pooled, Wt, bc, targets, pmax, psum, tlog);
    reduce_kernel<<<NROWS, 256, 0, stream>>>(pmax, psum, tlog, targets, rowl);
    finalize_kernel<<<1, 256, 0, stream>>>(rowl, targets, out);
}

// Round 9
// 227.150 us; speedup vs baseline: 1.5571x; 1.0723x over previous
//
#include <hip/hip_runtime.h>
#include <math.h>

#define BB 16
#define SS 512
#define HH 768
#define WW 256
#define VV 32000
#define NROWS (BB*WW)          // 4096
#define NCHUNK 500             // 64-wide v chunks
#define BM 128
#define BN 128
#define BK 64                  // fp8: 64 bytes per row per k-tile
#define NKT (HH/BK)            // 12
#define NMT (NROWS/BM)         // 32
#define NVT (VV/BN)            // 250
#define NWG (NMT*NVT)          // 8000
#define WSCALE 64.0f
#define WISCALE (1.0f/64.0f)

typedef __attribute__((ext_vector_type(4))) float f32x4;

#define GLOAD16(g, l) __builtin_amdgcn_global_load_lds( \
    (const __attribute__((address_space(1))) void*)(g), \
    (__attribute__((address_space(3))) void*)(l), 16, 0, 0)

// pack 4 floats -> 4 fp8 e4m3 bytes (OCP)
__device__ __forceinline__ unsigned int pk4_fp8(float a0, float a1, float a2, float a3) {
    int r = __builtin_amdgcn_cvt_pk_fp8_f32(a0, a1, 0, false);
    r = __builtin_amdgcn_cvt_pk_fp8_f32(a2, a3, r, true);
    return (unsigned int)r;
}

// ---------------- pooling: one block per (b, w), fp8 output ----------------
// Stored layout: within each 16B slot, the two 8B halves are swapped when
// row bit3 is set (feeds the conflict-free LDS read swizzle).
__global__ __launch_bounds__(256) void pool_kernel(
    const float* __restrict__ h, const int* __restrict__ wid,
    unsigned int* __restrict__ pooled32)   // 4096 x 192 u32 (=768 fp8)
{
    int blk = blockIdx.x;
    int b = blk >> 8;
    int w = blk & 255;
    int tid = threadIdx.x;
    __shared__ int s_wid[SS];
    for (int i = tid; i < SS; i += 256) s_wid[i] = wid[b*SS + i];
    __syncthreads();
    int lo = 0, hi = SS;
    while (lo < hi) { int mid = (lo + hi) >> 1; if (s_wid[mid] < w) lo = mid + 1; else hi = mid; }
    int start = lo;
    hi = SS;
    while (lo < hi) { int mid = (lo + hi) >> 1; if (s_wid[mid] <= w) lo = mid + 1; else hi = mid; }
    int end = lo;
    int cnt = end - start;

    if (tid < 192) {
        float4 a = {0.f, 0.f, 0.f, 0.f};
        const float* hb = h + (size_t)b*SS*HH;
        for (int s = start; s < end; ++s) {
            float4 r = *(const float4*)&hb[(size_t)s*HH + tid*4];
            a.x += r.x; a.y += r.y; a.z += r.z; a.w += r.w;
        }
        float inv = (cnt > 0) ? (1.0f / (float)cnt) : 0.0f;
        int p = (blk >> 3) & 1;                 // row bit3 -> swap 8B halves
        pooled32[blk*192 + (tid ^ (p << 1))] = pk4_fp8(a.x*inv, a.y*inv, a.z*inv, a.w*inv);
    }
}

// ------- convert + transpose W: (768,32000) f32 -> (32000,768) fp8 (x64 scale) -------
// Same half-swap-by-row-bit3 storage as pooled.
__global__ __launch_bounds__(256) void wt_kernel(
    const float* __restrict__ Wc, unsigned char* __restrict__ Wt)
{
    const int v0 = blockIdx.x * 64;
    const int k0 = blockIdx.y * 64;
    const int t = threadIdx.x;
    __shared__ float S[64][65];
    #pragma unroll
    for (int j = 0; j < 4; ++j) {
        int idx = t + j*256;
        int kr = idx >> 4;
        int vs = idx & 15;
        float4 f = *(const float4*)&Wc[(size_t)(k0+kr)*VV + v0 + vs*4];
        S[kr][vs*4+0] = f.x; S[kr][vs*4+1] = f.y;
        S[kr][vs*4+2] = f.z; S[kr][vs*4+3] = f.w;
    }
    __syncthreads();
    #pragma unroll
    for (int j = 0; j < 2; ++j) {
        int idx = t + j*256;
        int vi = idx >> 3;     // 0..63 (row within tile)
        int ks = idx & 7;      // 0..7 (8B seg)
        float f[8];
        #pragma unroll
        for (int i = 0; i < 8; ++i) f[i] = S[ks*8+i][vi] * WSCALE;
        uint2 o;
        o.x = pk4_fp8(f[0], f[1], f[2], f[3]);
        o.y = pk4_fp8(f[4], f[5], f[6], f[7]);
        int p = (vi >> 3) & 1;                  // row bit3 -> swap 8B halves
        *(uint2*)&Wt[(size_t)(v0+vi)*HH + k0 + (ks ^ p)*8] = o;
    }
}

// ---------------- fp8 MFMA GEMM, 128x128 tile, BK=64, 4 blocks/CU ----------------
// 256 threads = 4 waves (2M x 2N), wave tile 64x64, acc[4][4]=64 VGPR.
// LDS: 2 dbuf x (A 8KB + B 8KB) = 32 KB; launch_bounds(256,4) caps VGPR 128
// -> 4 blocks/CU = 16 waves in 4 independent barrier groups.
// m97-style loop: STAGE(kt+1) at top, compiler waits, one barrier per k-step.
// Swizzle (conflict-free): LDS 16B slot s of row r holds global slot
// s ^ ((r>>1)&3); global storage pre-swaps 8B halves by row bit3; read offset
// ((idx8>>1)^((r16>>1)&3))*16 + ((idx8&1)^((r16>>3)&1))*8 covers all 4 r16
// bits -> each 16-lane phase hits all 32 banks exactly once.
__global__ __launch_bounds__(256, 4) void logits_kernel(
    const unsigned char* __restrict__ Pb, const unsigned char* __restrict__ Wt,
    const float* __restrict__ bc, const int* __restrict__ targets,
    float* __restrict__ pmax, float* __restrict__ psum,
    float* __restrict__ tlogit)
{
    __shared__ unsigned char Alds[2][BM*BK];   // 2 x 8 KB
    __shared__ unsigned char Blds[2][BN*BK];   // 2 x 8 KB

    // XCD swizzle (NWG = 8000, divisible by 8), m-minor within XCD chunk
    const int id = blockIdx.x;
    const int wg = (id & 7) * (NWG/8) + (id >> 3);
    const int mt = wg % NMT;
    const int vt = wg / NMT;

    const int t = threadIdx.x;
    const int w = t >> 6;           // wave 0..3
    const int lane = t & 63;
    const int r16 = lane & 15;
    const int kb = lane >> 4;       // 0..3 (8-byte k-seg within 32)
    const int wr = w >> 1;          // 0..1 (M)
    const int wc = w & 1;           // 0..1 (N)
    const int row0 = mt * BM;
    const int v0 = vt * BN;

    // staging: one call = 64 lanes x 16 B = 16 rows x 64 B; lane = rr*4 + s
    const int rr = lane >> 2;                     // 0..15 row within call
    const int sg = (lane & 3) ^ ((rr >> 1) & 3);  // pre-swizzled global 16B slot

    // A: 8 calls (2/wave), B: 8 calls (2/wave) -> 4 loads/thread per STAGE
    #define STAGE(BUF, KT) do {                                                   \
        const int k0_ = (KT) * BK;                                                \
        _Pragma("unroll")                                                         \
        for (int j_ = 0; j_ < 2; ++j_) {                                          \
            int ca_ = w*2 + j_;                                                   \
            GLOAD16(Pb + (size_t)(row0 + ca_*16 + rr)*HH + k0_ + sg*16,           \
                    &Alds[BUF][ca_*1024]);                                        \
            GLOAD16(Wt + (size_t)(v0 + ca_*16 + rr)*HH + k0_ + sg*16,             \
                    &Blds[BUF][ca_*1024]);                                        \
        }                                                                         \
    } while (0)

    f32x4 acc[4][4];
    #pragma unroll
    for (int mf = 0; mf < 4; ++mf)
        #pragma unroll
        for (int nf = 0; nf < 4; ++nf)
            acc[mf][nf] = (f32x4){0.f, 0.f, 0.f, 0.f};

    STAGE(0, 0);
    __syncthreads();

    const int swz2 = (r16 >> 1) & 3;
    const int swz3 = (r16 >> 3) & 1;

    for (int kt = 0; kt < NKT; ++kt) {
        const int buf = kt & 1;
        if (kt + 1 < NKT) STAGE(buf ^ 1, kt + 1);

        long af[4][2], bfv[4][2];
        #pragma unroll
        for (int ks = 0; ks < 2; ++ks) {
            const int idx8 = ks*4 + kb;                       // 0..7
            const int off = (((idx8 >> 1) ^ swz2) << 4) | (((idx8 & 1) ^ swz3) << 3);
            #pragma unroll
            for (int mf = 0; mf < 4; ++mf)
                af[mf][ks] = *(const long*)&Alds[buf][(wr*64 + mf*16 + r16)*BK + off];
            #pragma unroll
            for (int nf = 0; nf < 4; ++nf)
                bfv[nf][ks] = *(const long*)&Blds[buf][(wc*64 + nf*16 + r16)*BK + off];
        }

        #pragma unroll
        for (int ks = 0; ks < 2; ++ks)
            #pragma unroll
            for (int mf = 0; mf < 4; ++mf)
                #pragma unroll
                for (int nf = 0; nf < 4; ++nf)
                    acc[mf][nf] = __builtin_amdgcn_mfma_f32_16x16x32_fp8_fp8(
                        af[mf][ks], bfv[nf][ks], acc[mf][nf], 0, 0, 0);

        __syncthreads();
    }

    // epilogue: unscale + bias + per-row max/sumexp over this wave's 64 cols
    const int cchunk = vt*2 + wc;
    float bias[4];
    #pragma unroll
    for (int nf = 0; nf < 4; ++nf) bias[nf] = bc[v0 + wc*64 + nf*16 + r16];

    #pragma unroll
    for (int mf = 0; mf < 4; ++mf) {
        #pragma unroll
        for (int j = 0; j < 4; ++j) {
            const int row = row0 + wr*64 + mf*16 + kb*4 + j;
            float v[4]; float mx = -INFINITY;
            #pragma unroll
            for (int nf = 0; nf < 4; ++nf) {
                v[nf] = acc[mf][nf][j]*WISCALE + bias[nf];
                mx = fmaxf(mx, v[nf]);
            }
            #pragma unroll
            for (int off = 1; off < 16; off <<= 1)
                mx = fmaxf(mx, __shfl_xor(mx, off, 16));
            float se = 0.f;
            #pragma unroll
            for (int nf = 0; nf < 4; ++nf) se += __expf(v[nf] - mx);
            #pragma unroll
            for (int off = 1; off < 16; off <<= 1)
                se += __shfl_xor(se, off, 16);
            if (r16 == 0) {
                pmax[(size_t)row*NCHUNK + cchunk] = mx;
                psum[(size_t)row*NCHUNK + cchunk] = se;
            }
            int tg = targets[row];
            int base = v0 + wc*64 + r16;
            #pragma unroll
            for (int nf = 0; nf < 4; ++nf)
                if (tg == base + nf*16) tlogit[row] = v[nf];
        }
    }
}

// ---------------- combine chunk partials -> per-row loss ----------------
__global__ __launch_bounds__(256) void reduce_kernel(
    const float* __restrict__ pmax, const float* __restrict__ psum,
    const float* __restrict__ tlogit, const int* __restrict__ targets,
    float* __restrict__ rowloss)
{
    const int row = blockIdx.x;
    const int tid = threadIdx.x;
    float m0 = (tid       < NCHUNK) ? pmax[(size_t)row*NCHUNK + tid]       : -INFINITY;
    float m1 = (tid + 256 < NCHUNK) ? pmax[(size_t)row*NCHUNK + tid + 256] : -INFINITY;
    float mw = fmaxf(m0, m1);
    #pragma unroll
    for (int off = 1; off < 64; off <<= 1)
        mw = fmaxf(mw, __shfl_xor(mw, off));
    __shared__ float smax[4];
    __shared__ float ssum[4];
    const int wave = tid >> 6;
    if ((tid & 63) == 0) smax[wave] = mw;
    __syncthreads();
    float mx = fmaxf(fmaxf(smax[0], smax[1]), fmaxf(smax[2], smax[3]));
    float s = 0.f;
    if (tid       < NCHUNK) s += psum[(size_t)row*NCHUNK + tid]       * __expf(m0 - mx);
    if (tid + 256 < NCHUNK) s += psum[(size_t)row*NCHUNK + tid + 256] * __expf(m1 - mx);
    #pragma unroll
    for (int off = 1; off < 64; off <<= 1)
        s += __shfl_xor(s, off);
    if ((tid & 63) == 0) ssum[wave] = s;
    __syncthreads();
    if (tid == 0) {
        float st = ssum[0] + ssum[1] + ssum[2] + ssum[3];
        float lse = mx + logf(st);
        int tg = targets[row];
        rowloss[row] = (tg != 0) ? (lse - tlogit[row]) : 0.0f;
    }
}

// ---------------- final sum over rows ----------------
__global__ __launch_bounds__(256) void finalize_kernel(
    const float* __restrict__ rowloss, const int* __restrict__ targets,
    float* __restrict__ out)
{
    const int tid = threadIdx.x;
    float s = 0.f; float c = 0.f;
    for (int i = tid; i < NROWS; i += 256) {
        s += rowloss[i];
        c += (targets[i] != 0) ? 1.0f : 0.0f;
    }
    #pragma unroll
    for (int off = 1; off < 64; off <<= 1) {
        s += __shfl_xor(s, off);
        c += __shfl_xor(c, off);
    }
    __shared__ float ss[4], sc[4];
    const int wave = tid >> 6;
    if ((tid & 63) == 0) { ss[wave] = s; sc[wave] = c; }
    __syncthreads();
    if (tid == 0) {
        float st = ss[0]+ss[1]+ss[2]+ss[3];
        float ct = sc[0]+sc[1]+sc[2]+sc[3];
        out[0] = st / fmaxf(ct, 1.0f);
    }
}

extern "C" void kernel_launch(void* const* d_in, const int* in_sizes, int n_in,
                              void* d_out, int out_size, void* d_ws, size_t ws_size,
                              hipStream_t stream) {
    const float* h       = (const float*)d_in[0];   // (16,512,768) f32
    const int*   wid     = (const int*)  d_in[1];   // (16,512) i32
    const int*   targets = (const int*)  d_in[2];   // (16,256) i32
    const float* Wc      = (const float*)d_in[3];   // (768,32000) f32
    const float* bc      = (const float*)d_in[4];   // (32000,) f32
    float* out = (float*)d_out;

    unsigned char* pooled = (unsigned char*)d_ws;                // 4096*768 fp8
    unsigned char* Wt     = pooled + (size_t)NROWS*HH;           // 32000*768 fp8
    float* pmax  = (float*)(Wt + (size_t)HH*VV);                 // 4096*500
    float* psum  = pmax + (size_t)NROWS*NCHUNK;                  // 4096*500
    float* tlog  = psum + (size_t)NROWS*NCHUNK;                  // 4096
    float* rowl  = tlog + NROWS;                                 // 4096

    pool_kernel<<<NROWS, 256, 0, stream>>>(h, wid, (unsigned int*)pooled);
    wt_kernel<<<dim3(VV/64, HH/64), 256, 0, stream>>>(Wc, Wt);
    logits_kernel<<<NWG, 256, 0, stream>>>(
        pooled, Wt, bc, targets, pmax, psum, tlog);
    reduce_kernel<<<NROWS, 256, 0, stream>>>(pmax, psum, tlog, targets, rowl);
    finalize_kernel<<<1, 256, 0, stream>>>(rowl, targets, out);
}